// Round 12
// baseline (252.242 us; speedup 1.0000x reference)
//
#include <hip/hip_runtime.h>
#include <hip/hip_bf16.h>
#include <stdint.h>

// ===================================================================
// PriorLayer online BP scan, round 14. s_t = norm(diag(p_t) T s_{t-1}).
// 13-round verdict: per-epoch ~2.2-2.4us invariant under body, waves,
// barriers, conflicts, code size, access pattern; R11 showed counters
// DON'T scale with 2x concurrent instances (per-CU serialization);
// R13 killed the bytes/2.2TB/s model (same bytes, coalesced, SLOWER).
// Sole surviving shared structure: the per-epoch inter-wave LDS
// exchange + barrier. R8 tried deleting it but was confounded (A in
// LDS -> per-MFMA ds_read serialization).
// R14: BARRIER-FREE AUTONOMOUS WAVES, A-residency fixed:
//  - 256 blocks x 1 wave; each wave owns 16 chunks, does the FULL
//    256-dim matvec (128 MFMAs/epoch); T in per-block LDS (128KB,
//    fragment-major, R8-verified layout) streamed through an explicit
//    2-stage A-register ring (aE/aO[16], ~330 VGPR, 1 wave/SIMD).
//  - State stays in the wave: next B built from C/D regs via 4-lane
//    permute net (cvt_pk_bf16 + ds_bpermute + select), reproducing
//    the R7-verified SB write/read maps exactly.
//  - ZERO barriers after init; zero inter-wave deps; no state LDS.
//  - CLEN=16, BURN=6 (R10-validated); state carried f32, quantized
//    to bf16 only at the MFMA operand (same quantization as before).
//  - P loads JIT at epoch start (16 scattered f32x4; ~950cyc slack
//    to first use covers HBM latency).
// ===================================================================

#define DIM   256
#define SEQ   65536
#define G     16                    // chunks per wave (MFMA cols)
#define CLEN  16                    // outputs per chunk
#define NBLK  (SEQ / (G * CLEN))    // 256 blocks -> 1 per CU
#define BURN  6
#define STEPS (BURN + CLEN)         // 22
#define TPB   64                    // ONE wave per block
#define LDS_BYTES (DIM * DIM * 2)   // 131072: T as bf16 fragments

typedef short bf16x8 __attribute__((ext_vector_type(8)));
typedef float f32x4  __attribute__((ext_vector_type(4)));

static __device__ __forceinline__ unsigned short f2bf(float x) {
  __hip_bfloat16 h = __float2bfloat16(x);
  return *reinterpret_cast<unsigned short*>(&h);
}

static __device__ __forceinline__ unsigned cvt_pk_bf16(float lo, float hi) {
  unsigned r;
  asm("v_cvt_pk_bf16_f32 %0, %1, %2" : "=v"(r) : "v"(lo), "v"(hi));
  return r;
}

__global__ __launch_bounds__(TPB, 1)
void prior_scan_kernel(const float* __restrict__ probs,
                       const float* __restrict__ tp,
                       float* __restrict__ out) {
  extern __shared__ short TA[];     // [rt][kb][qd*16+m][j] bf16 of T
  const int tid  = threadIdx.x;
  const int lane = tid;             // 1 wave
  const int n    = lane & 15;       // chunk col
  const int qd   = lane >> 4;
  const int g    = blockIdx.x * G + n;     // this lane's chunk id

  // ---- stage T into fragment-major bf16 (R8-verified formulas)
  //      element (r,c): rt=r>>4, m=r&15, kb=c>>5, qdd=(c>>3)&3, j0=c&7
  for (int s = tid * 4; s < DIM * DIM; s += TPB * 4) {
    const int r = s >> 8, c = s & 255;
    const int rt = r >> 4, m = r & 15;
    const int kb = c >> 5, qdd = (c >> 3) & 3, j0 = c & 7;   // j0 in {0,4}
    f32x4 f = *reinterpret_cast<const f32x4*>(tp + s);
    ushort4 v;
    v.x = f2bf(f[0]); v.y = f2bf(f[1]); v.z = f2bf(f[2]); v.w = f2bf(f[3]);
    *reinterpret_cast<ushort4*>(
        TA + ((rt * 8 + kb) * 64 + qdd * 16 + m) * 8 + j0) = v;
  }

  // ---- state in registers: C[rt][v] = u[rt*16+qd*4+v] of col n
  f32x4 C[16];
#pragma unroll
  for (int rt = 0; rt < 16; rt++)
    C[rt] = f32x4{0.00390625f, 0.00390625f, 0.00390625f, 0.00390625f};

  __syncthreads();                  // TA visible; LAST barrier of kernel

  // bpermute source lane addrs (bytes): u[r] lives in C[r>>4][r&3] of
  // lane ((r>>2)&3)*16+n. For B[kb] lane(qd,n): j0..3 from lane
  // 2(qd&1)*16+n, j4..7 from +16; tile rt=2kb+(qd>>1) (select a/b).
  const int sA = ((qd & 1) * 32 + n) << 2;
  const int sB = sA + (16 << 2);
  const bool hi = (qd >> 1) != 0;

  auto body = [&](int e, bool MAIN) {
    // --- issue P loads first (JIT; used after B-build + MFMAs)
    const int t = g * CLEN - BURN + e;
    const int tc = t < 0 ? 0 : t;
    f32x4 P[16];
#pragma unroll
    for (int rt = 0; rt < 16; rt++)
      P[rt] = *reinterpret_cast<const f32x4*>(
          probs + (size_t)tc * DIM + rt * 16 + qd * 4);

    // --- build B[8] from C (in-wave permute; C = state u_{t-1})
    bf16x8 B[8];
#pragma unroll
    for (int kb = 0; kb < 8; kb++) {
      unsigned d0a = cvt_pk_bf16(C[2 * kb][0],     C[2 * kb][1]);
      unsigned d1a = cvt_pk_bf16(C[2 * kb][2],     C[2 * kb][3]);
      unsigned d0b = cvt_pk_bf16(C[2 * kb + 1][0], C[2 * kb + 1][1]);
      unsigned d1b = cvt_pk_bf16(C[2 * kb + 1][2], C[2 * kb + 1][3]);
      int g0a = __builtin_amdgcn_ds_bpermute(sA, (int)d0a);
      int g0b = __builtin_amdgcn_ds_bpermute(sA, (int)d0b);
      int g1a = __builtin_amdgcn_ds_bpermute(sA, (int)d1a);
      int g1b = __builtin_amdgcn_ds_bpermute(sA, (int)d1b);
      int g2a = __builtin_amdgcn_ds_bpermute(sB, (int)d0a);
      int g2b = __builtin_amdgcn_ds_bpermute(sB, (int)d0b);
      int g3a = __builtin_amdgcn_ds_bpermute(sB, (int)d1a);
      int g3b = __builtin_amdgcn_ds_bpermute(sB, (int)d1b);
      int wi[4];
      wi[0] = hi ? g0b : g0a;       // j0,j1
      wi[1] = hi ? g1b : g1a;       // j2,j3
      wi[2] = hi ? g2b : g2a;       // j4,j5
      wi[3] = hi ? g3b : g3a;       // j6,j7
      B[kb] = *reinterpret_cast<bf16x8*>(wi);
    }

    // --- C = T @ u via A-register ring (LDS conflict-free b128)
    const short* ta = TA + lane * 8;
    const f32x4 Zv = {0.f, 0.f, 0.f, 0.f};
    bf16x8 aE[16], aO[16];
#pragma unroll
    for (int rt = 0; rt < 16; rt++)   // prefetch kb=0
      aE[rt] = *reinterpret_cast<const bf16x8*>(ta + rt * 4096);
#pragma unroll
    for (int kb = 0; kb < 8; kb += 2) {
#pragma unroll
      for (int rt = 0; rt < 16; rt++) // prefetch kb+1
        aO[rt] = *reinterpret_cast<const bf16x8*>(
            ta + rt * 4096 + (kb + 1) * 512);
#pragma unroll
      for (int rt = 0; rt < 16; rt++)
        C[rt] = __builtin_amdgcn_mfma_f32_16x16x32_bf16(
            aE[rt], B[kb], kb == 0 ? Zv : C[rt], 0, 0, 0);
      if (kb + 2 < 8) {
#pragma unroll
        for (int rt = 0; rt < 16; rt++) // prefetch kb+2
          aE[rt] = *reinterpret_cast<const bf16x8*>(
              ta + rt * 4096 + (kb + 2) * 512);
      }
#pragma unroll
      for (int rt = 0; rt < 16; rt++)
        C[rt] = __builtin_amdgcn_mfma_f32_16x16x32_bf16(
            aO[rt], B[kb + 1], C[rt], 0, 0, 0);
    }

    // --- C = (T u) .* p * 2^-6 ; pre-start clamp to uniform
#pragma unroll
    for (int rt = 0; rt < 16; rt++)
#pragma unroll
      for (int v = 0; v < 4; v++) {
        float qq = C[rt][v] * P[rt][v] * 0.015625f;
        C[rt][v] = (t < 0) ? 0.00390625f : qq;
      }

    if (MAIN) {
      // Z / entropy: lane-private 64-row sums + 2 shfl over quads
      float sz = 0.f, sl = 0.f;
#pragma unroll
      for (int rt = 0; rt < 16; rt++)
#pragma unroll
        for (int v = 0; v < 4; v++) {
          float qq = C[rt][v];
          sz += qq;
          sl += qq * __logf(qq + 1e-30f);
        }
      sz += __shfl_xor(sz, 16); sz += __shfl_xor(sz, 32);
      sl += __shfl_xor(sl, 16); sl += __shfl_xor(sl, 32);
      const float zi = __builtin_amdgcn_rcpf(sz);
#pragma unroll
      for (int rt = 0; rt < 16; rt++) {
        f32x4 o;
#pragma unroll
        for (int v = 0; v < 4; v++) o[v] = C[rt][v] * zi;
        *reinterpret_cast<f32x4*>(
            out + (size_t)t * DIM + rt * 16 + qd * 4) = o;
      }
      if (qd == 0)
        out[(size_t)SEQ * DIM + t] = __logf(sz) - sl * zi;
    }
  };

  // Rolled epoch loops; runtime e is fine (no parity state anywhere).
#pragma clang loop unroll(disable)
  for (int e = 0; e < BURN; e++)      body(e, false);
#pragma clang loop unroll(disable)
  for (int e = BURN; e < STEPS; e++)  body(e, true);
}

extern "C" void kernel_launch(void* const* d_in, const int* in_sizes, int n_in,
                              void* d_out, int out_size, void* d_ws, size_t ws_size,
                              hipStream_t stream) {
  const float* probs = (const float*)d_in[0];   // (65536, 256)
  const float* tp    = (const float*)d_in[1];   // (256, 256)
  float* out         = (float*)d_out;           // 65536*256 probs + 65536 H

  static bool configured = false;
  if (!configured) {
    hipFuncSetAttribute(reinterpret_cast<const void*>(prior_scan_kernel),
                        hipFuncAttributeMaxDynamicSharedMemorySize, LDS_BYTES);
    configured = true;
  }

  hipLaunchKernelGGL(prior_scan_kernel, dim3(NBLK), dim3(TPB), LDS_BYTES,
                     stream, probs, tp, out);
}